// Round 6
// baseline (537.554 us; speedup 1.0000x reference)
//
#include <hip/hip_runtime.h>
#include <hip/hip_cooperative_groups.h>
#include <hip/hip_bf16.h>
#include <cstdint>
#include <cstddef>

namespace cg = cooperative_groups;

#define NNODES 50000
#define NEDGES 800000
#define NCH    256
#define CHUNK1 3136                        // 255*3136 + 320 = 800000; every base 16B-aligned
#define NBUCK  196
#define GB1    782
#define SHB    64                          // degree-hist blocks per array
#define SHE    12500                       // 64*12500 = 800000
#define SHEV   (SHE / 1024)                // 12 full uint4 rounds
#define PBN    256
#define PBR    196

typedef unsigned short u16;
typedef unsigned int u32;
typedef short bfrag8 __attribute__((ext_vector_type(8)));
typedef float f32x4 __attribute__((ext_vector_type(4)));

__device__ __forceinline__ u16 f2bf(float f) {
    union { float f; uint32_t i; } v; v.f = f;
    uint32_t r = (v.i + 0x7FFFu + ((v.i >> 16) & 1u)) >> 16;
    return (u16)r;
}
__device__ __forceinline__ float bflo(u32 p) { union { uint32_t i; float f; } v; v.i = p << 16; return v.f; }
__device__ __forceinline__ float bfhi(u32 p) { union { uint32_t i; float f; } v; v.i = p & 0xFFFF0000u; return v.f; }

// ============ dense gemm body (verified r8-r11) ============
template <int K, int N, bool AF32>
__device__ __forceinline__ void gemm_body(const void* __restrict__ A_, const u16* __restrict__ Wp,
                                          const int* __restrict__ deg, u16* __restrict__ out, int M, int bx) {
    const int lane = threadIdx.x & 63;
    const int wave = threadIdx.x >> 6;
    const int m = lane & 15;
    const int q = lane >> 4;
    const int row0 = bx * 64 + wave * 16;
    int rowa = row0 + m; if (rowa > M - 1) rowa = M - 1;
    constexpr int NT = N / 16;
    f32x4 acc[NT];
    #pragma unroll
    for (int t = 0; t < NT; t++) acc[t] = (f32x4){0.f, 0.f, 0.f, 0.f};
    #pragma unroll
    for (int kc = 0; kc < K; kc += 32) {
        bfrag8 af;
        if constexpr (AF32) {
            const float* ap = (const float*)A_ + (size_t)rowa * K + q * 8 + kc;
            const float4 x0 = *(const float4*)(ap);
            const float4 x1 = *(const float4*)(ap + 4);
            af[0] = (short)f2bf(x0.x); af[1] = (short)f2bf(x0.y);
            af[2] = (short)f2bf(x0.z); af[3] = (short)f2bf(x0.w);
            af[4] = (short)f2bf(x1.x); af[5] = (short)f2bf(x1.y);
            af[6] = (short)f2bf(x1.z); af[7] = (short)f2bf(x1.w);
        } else {
            const u16* ap = (const u16*)A_ + (size_t)rowa * K + q * 8 + kc;
            af = *(const bfrag8*)ap;
        }
        const u16* bbase = Wp + ((size_t)(((kc >> 3) + q) * N) + m) * 8;
        #pragma unroll
        for (int t = 0; t < NT; t++) {
            bfrag8 bf_ = *(const bfrag8*)(bbase + t * 128);
            acc[t] = __builtin_amdgcn_mfma_f32_16x16x32_bf16(af, bf_, acc[t], 0, 0, 0);
        }
    }
    #pragma unroll
    for (int r = 0; r < 4; r++) {
        int gr = row0 + q * 4 + r;
        if (gr < M) {
            int dO = deg[gr]; if (dO < 1) dO = 1;
            float s = rsqrtf((float)dO);
            #pragma unroll
            for (int t = 0; t < NT; t++)
                out[(size_t)gr * N + t * 16 + m] = f2bf(acc[t][r] * s);
        }
    }
}

// ======================================================================================
// MEGA: whole pipeline in one cooperative dispatch. 25.6KB pooled LDS; all phases
// grid-stride; 4 grid.sync(). Phase math byte-identical to the 5-kernel pipeline.
// Deg-hist runs as two 25KB node-half passes (same counts, same histS/histD layout).
// ======================================================================================
__global__ __launch_bounds__(256, 4) void mega(
    const float* __restrict__ W1, const float* __restrict__ W2, const float* __restrict__ b1,
    const float* __restrict__ b2, const float* __restrict__ Wf, const float* __restrict__ bfv,
    const float* __restrict__ x, const int* __restrict__ src, const int* __restrict__ dst,
    u16* __restrict__ Wp1, u16* __restrict__ Wp2, u32* __restrict__ histS, u32* __restrict__ histD,
    u16* __restrict__ gh1, int* __restrict__ deg_out, int* __restrict__ deg_in,
    int* __restrict__ gdh, int* __restrict__ part1, u32* __restrict__ sbuf, u32* __restrict__ sorted,
    int* __restrict__ rp, int* __restrict__ perm, u16* __restrict__ h, u16* __restrict__ h2,
    float* __restrict__ logits, float* __restrict__ hidden)
{
    cg::grid_group grid = cg::this_grid();
    __shared__ __align__(16) u32 SM[6400];         // 25.6 KB pooled
    const int t = threadIdx.x;
    const int NB = gridDim.x;

    // ---------------- P1: deg hists | chunk hist | weight prep ----------------
    for (int vb = blockIdx.x; vb < 2 * SHB + NCH + 128; vb += NB) {
        if (vb < 2 * SHB) {
            const int* col = (vb < SHB) ? src : dst;
            int bb = (vb < SHB) ? vb : vb - SHB;
            u32* outp = ((vb < SHB) ? histS : histD) + (size_t)bb * 12500;
            const uint4* col4 = (const uint4*)(col + bb * SHE);
            #pragma unroll 1
            for (int half = 0; half < 2; half++) {
                u32 lo = half * 25000u, hiX = lo + 25000u;
                for (int j = t; j < 6250; j += 256) SM[j] = 0;
                __syncthreads();
                #pragma unroll 4
                for (int k = 0; k < SHEV; k++) {
                    uint4 e = col4[k * 256 + t];
                    if (e.x >= lo && e.x < hiX) atomicAdd(&SM[(e.x - lo) >> 2], 1u << ((e.x & 3) * 8));
                    if (e.y >= lo && e.y < hiX) atomicAdd(&SM[(e.y - lo) >> 2], 1u << ((e.y & 3) * 8));
                    if (e.z >= lo && e.z < hiX) atomicAdd(&SM[(e.z - lo) >> 2], 1u << ((e.z & 3) * 8));
                    if (e.w >= lo && e.w < hiX) atomicAdd(&SM[(e.w - lo) >> 2], 1u << ((e.w & 3) * 8));
                }
                for (int i = SHEV * 1024 + t; i < SHE; i += 256) {
                    u32 n = (u32)col[bb * SHE + i];
                    if (n >= lo && n < hiX) atomicAdd(&SM[(n - lo) >> 2], 1u << ((n & 3) * 8));
                }
                __syncthreads();
                for (int j = t; j < 6250; j += 256) outp[half * 6250 + j] = SM[j];
                __syncthreads();
            }
        } else if (vb < 2 * SHB + NCH) {
            int c = vb - 2 * SHB;
            SM[t] = 0;
            __syncthreads();
            int beg = c * CHUNK1, end = min(beg + CHUNK1, NEDGES);
            const uint4* d4 = (const uint4*)(dst + beg);
            int n4 = (end - beg) >> 2;
            for (int k = t; k < n4; k += 256) {
                uint4 e = d4[k];
                atomicAdd(&SM[e.x >> 8], 1u);
                atomicAdd(&SM[e.y >> 8], 1u);
                atomicAdd(&SM[e.z >> 8], 1u);
                atomicAdd(&SM[e.w >> 8], 1u);
            }
            __syncthreads();
            gh1[c * NCH + t] = (u16)SM[t];         // [chunk][digit]
            __syncthreads();
        } else {
            int i = (vb - 2 * SHB - NCH) * 256 + t;
            if (i < 256 * 128) {
                int k = i >> 7, n = i & 127;
                Wp1[((((k >> 3) << 7) + n) << 3) | (k & 7)] = f2bf(W1[i]);
            }
            if (i < 128 * 64) {
                int k = i >> 6, n = i & 63;
                Wp2[((((k >> 3) << 6) + n) << 3) | (k & 7)] = f2bf(W2[i]);
            }
            __syncthreads();
        }
    }
    grid.sync();

    // ---------------- P2: partition scatter + deg reduce + gdh ----------------
    {
        int* sd    = (int*)SM;                     // [0,256)
        u32* base  = SM + 256;                     // [256,512)
        u32* lh    = SM + 512;                     // [512,768)
        int* cnt64 = (int*)SM + 768;               // [768,832)
        for (int c = blockIdx.x; c < NCH; c += NB) {
            if (t < 64) cnt64[t] = 0;
            int tot = 0, par = 0;
            #pragma unroll 8
            for (int cc = 0; cc < NCH; cc++) {
                int v = (int)gh1[cc * NCH + t];
                tot += v;
                par += (cc < c) ? v : 0;
            }
            if (c == 0) part1[t] = tot;
            sd[t] = tot;
            __syncthreads();
            #pragma unroll
            for (int o = 1; o < 256; o <<= 1) {
                int add = (t >= o) ? sd[t - o] : 0;
                __syncthreads();
                sd[t] += add;
                __syncthreads();
            }
            base[t] = (u32)((sd[t] - tot) + par);
            lh[t] = 0;
            __syncthreads();
            int beg = c * CHUNK1, end = min(beg + CHUNK1, NEDGES);
            const uint4* s4 = (const uint4*)(src + beg);
            const uint4* d4 = (const uint4*)(dst + beg);
            int n4 = (end - beg) >> 2;
            for (int k = t; k < n4; k += 256) {
                uint4 es = s4[k], ed = d4[k];
                u32 el, dg, r;
                el = (ed.x << 16) | es.x; dg = el >> 24; r = atomicAdd(&lh[dg], 1); sbuf[base[dg] + r] = el;
                el = (ed.y << 16) | es.y; dg = el >> 24; r = atomicAdd(&lh[dg], 1); sbuf[base[dg] + r] = el;
                el = (ed.z << 16) | es.z; dg = el >> 24; r = atomicAdd(&lh[dg], 1); sbuf[base[dg] + r] = el;
                el = (ed.w << 16) | es.w; dg = el >> 24; r = atomicAdd(&lh[dg], 1); sbuf[base[dg] + r] = el;
            }
            int n = c * PBR + t;
            if (t < PBR && n < NNODES) {
                int w = n >> 2, sh = (n & 3) * 8;
                int so = 0, si = 0;
                #pragma unroll 8
                for (int r = 0; r < SHB; r++) {
                    so += (int)((histS[(size_t)r * 12500 + w] >> sh) & 255u);
                    si += (int)((histD[(size_t)r * 12500 + w] >> sh) & 255u);
                }
                deg_out[n] = so;
                deg_in[n] = si;
                atomicAdd(&cnt64[si > 63 ? 63 : si], 1);
            }
            __syncthreads();
            if (t < 64) gdh[c * 64 + t] = cnt64[t];
            __syncthreads();
        }
    }
    grid.sync();

    // ---------------- P3: bucket sort + row_ptr | layer-1 gemm | perm ----------------
    for (int vb = blockIdx.x; vb < NBUCK + GB1 + PBN; vb += NB) {
        if (vb < NBUCK) {
            int* sd     = (int*)SM;
            int* cnt    = (int*)SM + 256;
            int* cursor = (int*)SM + 512;
            int* bsbl   = (int*)SM + 768;
            int v = part1[t];
            sd[t] = v;
            __syncthreads();
            #pragma unroll
            for (int o = 1; o < 256; o <<= 1) {
                int add = (t >= o) ? sd[t - o] : 0;
                __syncthreads();
                sd[t] += add;
                __syncthreads();
            }
            if (t == vb) { bsbl[0] = sd[t] - v; bsbl[1] = v; }
            __syncthreads();
            int bstart = bsbl[0], bend = bstart + bsbl[1];
            cnt[t] = 0;
            __syncthreads();
            for (int i = bstart + t; i < bend; i += 256)
                atomicAdd(&cnt[(sbuf[i] >> 16) & 255u], 1);
            __syncthreads();
            int cv = cnt[t];
            sd[t] = cv;
            __syncthreads();
            #pragma unroll
            for (int o = 1; o < 256; o <<= 1) {
                int add = (t >= o) ? sd[t - o] : 0;
                __syncthreads();
                sd[t] += add;
                __syncthreads();
            }
            int excl = sd[t] - cv;
            int node = vb * 256 + t;
            if (node < NNODES) rp[node] = bstart + excl;
            if (vb == NBUCK - 1 && t == 0) rp[NNODES] = NEDGES;
            cursor[t] = excl;
            __syncthreads();
            for (int i = bstart + t; i < bend; i += 256) {
                u32 el = sbuf[i];
                int r = atomicAdd(&cursor[(el >> 16) & 255u], 1);
                sorted[bstart + r] = el;
            }
            __syncthreads();
        } else if (vb < NBUCK + GB1) {
            gemm_body<256, 128, true>(x, Wp1, deg_out, h, NNODES, vb - NBUCK);
            __syncthreads();
        } else {
            int pb = vb - NBUCK - GB1;
            int* cse = (int*)SM;
            int* cur = (int*)SM + 64;
            if (t < 64) {
                int s_all = 0, s_pre = 0;
                for (int q2 = 0; q2 < PBN; q2++) {
                    int v = gdh[q2 * 64 + t];
                    s_all += v;
                    s_pre += (q2 < pb) ? v : 0;
                }
                cse[t] = s_all;
                cur[t] = s_pre;
            }
            __syncthreads();
            if (t == 0) {
                int s = 0;
                for (int d2 = 0; d2 < 64; d2++) { int v = cse[d2]; cse[d2] = s; s += v; }
            }
            __syncthreads();
            if (t < 64) cur[t] += cse[t];
            __syncthreads();
            int n = pb * PBR + t;
            if (t < PBR && n < NNODES) {
                int d = deg_in[n]; d = d > 63 ? 63 : d;
                int p = atomicAdd(&cur[d], 1);
                perm[p] = n;
            }
            __syncthreads();
        }
    }
    grid.sync();

    // ---------------- P4: layer-1 gather fused with layer-2 gemm ----------------
    {
        u16* sh = (u16*)SM;                        // 16 x 136 bf16 = 4352 B
        const uint4* h4 = (const uint4*)h;
        int qw = t >> 4, l = t & 15;
        const int lane = t & 63, m = lane & 15, q = lane >> 4, w = t >> 6;
        for (int vb = blockIdx.x; vb < NNODES / 16; vb += NB) {
            int node = perm[vb * 16 + qw];
            int beg = rp[node], end = rp[node + 1];
            float a[8] = {0.f, 0.f, 0.f, 0.f, 0.f, 0.f, 0.f, 0.f};
            for (int e = beg; e < end; e += 8) {
                uint4 p[8];
                #pragma unroll
                for (int j = 0; j < 8; j++) {
                    int ee = e + j; ee = (ee < end - 1) ? ee : end - 1;
                    p[j] = h4[(size_t)(sorted[ee] & 0xFFFFu) * 16 + l];
                }
                #pragma unroll
                for (int j = 0; j < 8; j++)
                    if (e + j < end) {
                        a[0] += bflo(p[j].x); a[1] += bfhi(p[j].x);
                        a[2] += bflo(p[j].y); a[3] += bfhi(p[j].y);
                        a[4] += bflo(p[j].z); a[5] += bfhi(p[j].z);
                        a[6] += bflo(p[j].w); a[7] += bfhi(p[j].w);
                    }
            }
            int dI = end - beg; if (dI < 1) dI = 1;
            float r = rsqrtf((float)dI);
            const float4 bA = *(const float4*)(b1 + 8 * l);
            const float4 bB = *(const float4*)(b1 + 8 * l + 4);
            float v0 = fmaxf(a[0] * r + bA.x, 0.f), v1 = fmaxf(a[1] * r + bA.y, 0.f);
            float v2 = fmaxf(a[2] * r + bA.z, 0.f), v3 = fmaxf(a[3] * r + bA.w, 0.f);
            float v4 = fmaxf(a[4] * r + bB.x, 0.f), v5 = fmaxf(a[5] * r + bB.y, 0.f);
            float v6 = fmaxf(a[6] * r + bB.z, 0.f), v7 = fmaxf(a[7] * r + bB.w, 0.f);
            uint4 o;
            o.x = ((u32)f2bf(v1) << 16) | f2bf(v0);
            o.y = ((u32)f2bf(v3) << 16) | f2bf(v2);
            o.z = ((u32)f2bf(v5) << 16) | f2bf(v4);
            o.w = ((u32)f2bf(v7) << 16) | f2bf(v6);
            *(uint4*)&sh[qw * 136 + l * 8] = o;
            __syncthreads();
            f32x4 acc = (f32x4){0.f, 0.f, 0.f, 0.f};
            #pragma unroll
            for (int kc = 0; kc < 128; kc += 32) {
                bfrag8 af = *(const bfrag8*)&sh[m * 136 + q * 8 + kc];
                bfrag8 bf_ = *(const bfrag8*)(Wp2 + ((size_t)(((kc >> 3) + q) * 64) + w * 16 + m) * 8);
                acc = __builtin_amdgcn_mfma_f32_16x16x32_bf16(af, bf_, acc, 0, 0, 0);
            }
            #pragma unroll
            for (int rr = 0; rr < 4; rr++) {
                int li = q * 4 + rr;
                int nd = perm[vb * 16 + li];
                int dO = deg_out[nd]; if (dO < 1) dO = 1;
                float s = rsqrtf((float)dO);
                h2[(size_t)nd * 64 + w * 16 + m] = f2bf(acc[rr] * s);
            }
            __syncthreads();                       // before next iteration overwrites sh
        }
    }
    grid.sync();

    // ---------------- P5: layer-2 gather + projection ----------------
    {
        const uint4* h24 = (const uint4*)h2;
        int l = t & 7;
        for (int vb = blockIdx.x; vb < (NNODES * 8 + 255) / 256; vb += NB) {
            int g = vb * 32 + (t >> 3);
            if (g < NNODES) {
                int node = perm[g];
                int beg = rp[node], end = rp[node + 1];
                float a[8] = {0.f, 0.f, 0.f, 0.f, 0.f, 0.f, 0.f, 0.f};
                for (int e = beg; e < end; e += 8) {
                    uint4 p[8];
                    #pragma unroll
                    for (int j = 0; j < 8; j++) {
                        int ee = e + j; ee = (ee < end - 1) ? ee : end - 1;
                        p[j] = h24[(size_t)(sorted[ee] & 0xFFFFu) * 8 + l];
                    }
                    #pragma unroll
                    for (int j = 0; j < 8; j++)
                        if (e + j < end) {
                            a[0] += bflo(p[j].x); a[1] += bfhi(p[j].x);
                            a[2] += bflo(p[j].y); a[3] += bfhi(p[j].y);
                            a[4] += bflo(p[j].z); a[5] += bfhi(p[j].z);
                            a[6] += bflo(p[j].w); a[7] += bfhi(p[j].w);
                        }
                }
                int dI = end - beg; if (dI < 1) dI = 1;
                float r = rsqrtf((float)dI);
                float v[8];
                #pragma unroll
                for (int f = 0; f < 8; f++) v[f] = a[f] * r + b2[8 * l + f];
                float4 oA = {v[0], v[1], v[2], v[3]};
                float4 oB = {v[4], v[5], v[6], v[7]};
                ((float4*)hidden)[(size_t)node * 16 + 2 * l + 0] = oA;
                ((float4*)hidden)[(size_t)node * 16 + 2 * l + 1] = oB;
                float l0 = 0.f, l1 = 0.f;
                #pragma unroll
                for (int f = 0; f < 8; f++) {
                    l0 += v[f] * Wf[(8 * l + f) * 2 + 0];
                    l1 += v[f] * Wf[(8 * l + f) * 2 + 1];
                }
                #pragma unroll
                for (int off2 = 4; off2 > 0; off2 >>= 1) {
                    l0 += __shfl_down(l0, off2, 8);
                    l1 += __shfl_down(l1, off2, 8);
                }
                if (l == 0) {
                    logits[(size_t)node * 2 + 0] = l0 + bfv[0];
                    logits[(size_t)node * 2 + 1] = l1 + bfv[1];
                }
            }
        }
    }
}

// ======================================================================================
// Fallback 5-kernel pipeline (round-5, verified) — used only if cooperative launch fails.
// ======================================================================================
__global__ __launch_bounds__(256) void pre_kernel(const float* __restrict__ W1, const float* __restrict__ W2,
                                                  u16* __restrict__ P1, u16* __restrict__ P2,
                                                  const int* __restrict__ src, const int* __restrict__ dst,
                                                  u32* __restrict__ histS, u32* __restrict__ histD,
                                                  u16* __restrict__ gh1, int nE) {
    __shared__ u32 hh[12500];
    int b = blockIdx.x, t = threadIdx.x;
    if (b < 2 * SHB) {
        const int* col = (b < SHB) ? src : dst;
        int bb = (b < SHB) ? b : b - SHB;
        for (int j = t; j < 12500; j += 256) hh[j] = 0;
        __syncthreads();
        int beg = bb * SHE;
        const uint4* col4 = (const uint4*)(col + beg);
        #pragma unroll 4
        for (int k = 0; k < SHEV; k++) {
            uint4 e = col4[k * 256 + t];
            atomicAdd(&hh[e.x >> 2], 1u << ((e.x & 3) * 8));
            atomicAdd(&hh[e.y >> 2], 1u << ((e.y & 3) * 8));
            atomicAdd(&hh[e.z >> 2], 1u << ((e.z & 3) * 8));
            atomicAdd(&hh[e.w >> 2], 1u << ((e.w & 3) * 8));
        }
        for (int i = beg + SHEV * 1024 + t; i < beg + SHE; i += 256) {
            u32 n = (u32)col[i];
            atomicAdd(&hh[n >> 2], 1u << ((n & 3) * 8));
        }
        __syncthreads();
        u32* out = ((b < SHB) ? histS : histD) + (size_t)bb * 12500;
        for (int j = t; j < 12500; j += 256) out[j] = hh[j];
    } else if (b < 2 * SHB + NCH) {
        int c = b - 2 * SHB;
        hh[t] = 0;
        __syncthreads();
        int beg = c * CHUNK1, end = min(beg + CHUNK1, nE);
        const uint4* d4 = (const uint4*)(dst + beg);
        int n4 = (end - beg) >> 2;
        for (int k = t; k < n4; k += 256) {
            uint4 e = d4[k];
            atomicAdd(&hh[e.x >> 8], 1u);
            atomicAdd(&hh[e.y >> 8], 1u);
            atomicAdd(&hh[e.z >> 8], 1u);
            atomicAdd(&hh[e.w >> 8], 1u);
        }
        __syncthreads();
        gh1[c * NCH + t] = (u16)hh[t];
    } else {
        int i = (b - 2 * SHB - NCH) * 256 + t;
        if (i < 256 * 128) {
            int k = i >> 7, n = i & 127;
            P1[((((k >> 3) << 7) + n) << 3) | (k & 7)] = f2bf(W1[i]);
        }
        if (i < 128 * 64) {
            int k = i >> 6, n = i & 63;
            P2[((((k >> 3) << 6) + n) << 3) | (k & 7)] = f2bf(W2[i]);
        }
    }
}

__global__ __launch_bounds__(256) void scat_deg(const int* __restrict__ src, const int* __restrict__ dst,
                                                const u16* __restrict__ gh1,
                                                const u32* __restrict__ histS, const u32* __restrict__ histD,
                                                int* __restrict__ deg_out, int* __restrict__ deg_in,
                                                int* __restrict__ gdh, int* __restrict__ part1,
                                                u32* __restrict__ sbuf, int nE) {
    int t = threadIdx.x, c = blockIdx.x;
    __shared__ int sd[256];
    __shared__ u32 base[256];
    __shared__ u32 lh[256];
    __shared__ int cnt64[64];
    if (t < 64) cnt64[t] = 0;
    int tot = 0, par = 0;
    #pragma unroll 8
    for (int cc = 0; cc < NCH; cc++) {
        int v = (int)gh1[cc * NCH + t];
        tot += v;
        par += (cc < c) ? v : 0;
    }
    if (c == 0) part1[t] = tot;
    sd[t] = tot;
    __syncthreads();
    #pragma unroll
    for (int o = 1; o < 256; o <<= 1) {
        int add = (t >= o) ? sd[t - o] : 0;
        __syncthreads();
        sd[t] += add;
        __syncthreads();
    }
    base[t] = (u32)((sd[t] - tot) + par);
    lh[t] = 0;
    __syncthreads();
    int beg = c * CHUNK1, end = min(beg + CHUNK1, nE);
    const uint4* s4 = (const uint4*)(src + beg);
    const uint4* d4 = (const uint4*)(dst + beg);
    int n4 = (end - beg) >> 2;
    for (int k = t; k < n4; k += 256) {
        uint4 es = s4[k], ed = d4[k];
        u32 el, dg, r;
        el = (ed.x << 16) | es.x; dg = el >> 24; r = atomicAdd(&lh[dg], 1); sbuf[base[dg] + r] = el;
        el = (ed.y << 16) | es.y; dg = el >> 24; r = atomicAdd(&lh[dg], 1); sbuf[base[dg] + r] = el;
        el = (ed.z << 16) | es.z; dg = el >> 24; r = atomicAdd(&lh[dg], 1); sbuf[base[dg] + r] = el;
        el = (ed.w << 16) | es.w; dg = el >> 24; r = atomicAdd(&lh[dg], 1); sbuf[base[dg] + r] = el;
    }
    int n = c * PBR + t;
    if (t < PBR && n < NNODES) {
        int w = n >> 2, sh = (n & 3) * 8;
        int so = 0, si = 0;
        #pragma unroll 8
        for (int r = 0; r < SHB; r++) {
            so += (int)((histS[(size_t)r * 12500 + w] >> sh) & 255u);
            si += (int)((histD[(size_t)r * 12500 + w] >> sh) & 255u);
        }
        deg_out[n] = so;
        deg_in[n] = si;
        atomicAdd(&cnt64[si > 63 ? 63 : si], 1);
    }
    __syncthreads();
    if (t < 64) gdh[c * 64 + t] = cnt64[t];
}

__global__ __launch_bounds__(256) void sort_gemm(const u32* __restrict__ sbuf, const int* __restrict__ part1,
                                                 u32* __restrict__ sorted, int* __restrict__ rp,
                                                 const float* __restrict__ x, const u16* __restrict__ Wp1,
                                                 const int* __restrict__ deg_out, const int* __restrict__ deg_in,
                                                 const int* __restrict__ gdh, int* __restrict__ perm,
                                                 u16* __restrict__ h, int nE) {
    int b = blockIdx.x, t = threadIdx.x;
    if (b < NBUCK) {
        __shared__ int sd[256];
        __shared__ int cnt[256];
        __shared__ int cursor[256];
        int v = part1[t];
        sd[t] = v;
        __syncthreads();
        #pragma unroll
        for (int o = 1; o < 256; o <<= 1) {
            int add = (t >= o) ? sd[t - o] : 0;
            __syncthreads();
            sd[t] += add;
            __syncthreads();
        }
        __shared__ int bs_s, bl_s;
        if (t == b) { bs_s = sd[t] - v; bl_s = v; }
        __syncthreads();
        int bstart = bs_s, bend = bstart + bl_s;
        cnt[t] = 0;
        __syncthreads();
        for (int i = bstart + t; i < bend; i += 256)
            atomicAdd(&cnt[(sbuf[i] >> 16) & 255u], 1);
        __syncthreads();
        int cv = cnt[t];
        sd[t] = cv;
        __syncthreads();
        #pragma unroll
        for (int o = 1; o < 256; o <<= 1) {
            int add = (t >= o) ? sd[t - o] : 0;
            __syncthreads();
            sd[t] += add;
            __syncthreads();
        }
        int excl = sd[t] - cv;
        int node = b * 256 + t;
        if (node < NNODES) rp[node] = bstart + excl;
        if (b == NBUCK - 1 && t == 0) rp[NNODES] = nE;
        cursor[t] = excl;
        __syncthreads();
        for (int i = bstart + t; i < bend; i += 256) {
            u32 el = sbuf[i];
            int r = atomicAdd(&cursor[(el >> 16) & 255u], 1);
            sorted[bstart + r] = el;
        }
    } else if (b < NBUCK + GB1) {
        gemm_body<256, 128, true>(x, Wp1, deg_out, h, NNODES, b - NBUCK);
    } else {
        int pb = b - NBUCK - GB1;
        __shared__ int cse[64];
        __shared__ int cur[64];
        if (t < 64) {
            int s_all = 0, s_pre = 0;
            for (int q2 = 0; q2 < PBN; q2++) {
                int v = gdh[q2 * 64 + t];
                s_all += v;
                s_pre += (q2 < pb) ? v : 0;
            }
            cse[t] = s_all;
            cur[t] = s_pre;
        }
        __syncthreads();
        if (t == 0) {
            int s = 0;
            for (int d2 = 0; d2 < 64; d2++) { int v = cse[d2]; cse[d2] = s; s += v; }
        }
        __syncthreads();
        if (t < 64) cur[t] += cse[t];
        __syncthreads();
        int n = pb * PBR + t;
        if (t < PBR && n < NNODES) {
            int d = deg_in[n]; d = d > 63 ? 63 : d;
            int p = atomicAdd(&cur[d], 1);
            perm[p] = n;
        }
    }
}

__global__ __launch_bounds__(256) void gather1f(const uint4* __restrict__ h, const int* __restrict__ row_ptr,
                                                const u32* __restrict__ sorted, const float* __restrict__ b1,
                                                const int* __restrict__ perm, const int* __restrict__ deg_out,
                                                const u16* __restrict__ Wp2, u16* __restrict__ h2) {
    __shared__ __align__(16) u16 sh[16 * 136];
    int t = threadIdx.x;
    int qw = t >> 4;
    int l = t & 15;
    int g = blockIdx.x * 16 + qw;
    int node = perm[g];
    int beg = row_ptr[node], end = row_ptr[node + 1];
    float a[8] = {0.f, 0.f, 0.f, 0.f, 0.f, 0.f, 0.f, 0.f};
    for (int e = beg; e < end; e += 8) {
        uint4 p[8];
        #pragma unroll
        for (int j = 0; j < 8; j++) {
            int ee = e + j; ee = (ee < end - 1) ? ee : end - 1;
            p[j] = h[(size_t)(sorted[ee] & 0xFFFFu) * 16 + l];
        }
        #pragma unroll
        for (int j = 0; j < 8; j++)
            if (e + j < end) {
                a[0] += bflo(p[j].x); a[1] += bfhi(p[j].x);
                a[2] += bflo(p[j].y); a[3] += bfhi(p[j].y);
                a[4] += bflo(p[j].z); a[5] += bfhi(p[j].z);
                a[6] += bflo(p[j].w); a[7] += bfhi(p[j].w);
            }
    }
    int dI = end - beg; if (dI < 1) dI = 1;
    float r = rsqrtf((float)dI);
    const float4 bA = *(const float4*)(b1 + 8 * l);
    const float4 bB = *(const float4*)(b1 + 8 * l + 4);
    float v0 = fmaxf(a[0] * r + bA.x, 0.f), v1 = fmaxf(a[1] * r + bA.y, 0.f);
    float v2 = fmaxf(a[2] * r + bA.z, 0.f), v3 = fmaxf(a[3] * r + bA.w, 0.f);
    float v4 = fmaxf(a[4] * r + bB.x, 0.f), v5 = fmaxf(a[5] * r + bB.y, 0.f);
    float v6 = fmaxf(a[6] * r + bB.z, 0.f), v7 = fmaxf(a[7] * r + bB.w, 0.f);
    uint4 o;
    o.x = ((u32)f2bf(v1) << 16) | f2bf(v0);
    o.y = ((u32)f2bf(v3) << 16) | f2bf(v2);
    o.z = ((u32)f2bf(v5) << 16) | f2bf(v4);
    o.w = ((u32)f2bf(v7) << 16) | f2bf(v6);
    *(uint4*)&sh[qw * 136 + l * 8] = o;
    __syncthreads();
    const int lane = t & 63;
    const int m = lane & 15;
    const int q = lane >> 4;
    const int w = t >> 6;
    f32x4 acc = (f32x4){0.f, 0.f, 0.f, 0.f};
    #pragma unroll
    for (int kc = 0; kc < 128; kc += 32) {
        bfrag8 af = *(const bfrag8*)&sh[m * 136 + q * 8 + kc];
        bfrag8 bf_ = *(const bfrag8*)(Wp2 + ((size_t)(((kc >> 3) + q) * 64) + w * 16 + m) * 8);
        acc = __builtin_amdgcn_mfma_f32_16x16x32_bf16(af, bf_, acc, 0, 0, 0);
    }
    #pragma unroll
    for (int rr = 0; rr < 4; rr++) {
        int li = q * 4 + rr;
        int nd = perm[blockIdx.x * 16 + li];
        int dO = deg_out[nd]; if (dO < 1) dO = 1;
        float s = rsqrtf((float)dO);
        h2[(size_t)nd * 64 + w * 16 + m] = f2bf(acc[rr] * s);
    }
}

__global__ __launch_bounds__(256) void gather2(const uint4* __restrict__ h2, const int* __restrict__ row_ptr,
                                               const u32* __restrict__ sorted, const float* __restrict__ b2,
                                               const float* __restrict__ Wf, const float* __restrict__ bfv,
                                               const int* __restrict__ perm,
                                               float* __restrict__ logits, float* __restrict__ hidden, int nNodes) {
    int g = (blockIdx.x * 256 + threadIdx.x) >> 3;
    int l = threadIdx.x & 7;
    if (g >= nNodes) return;
    int node = perm[g];
    int beg = row_ptr[node], end = row_ptr[node + 1];
    float a[8] = {0.f, 0.f, 0.f, 0.f, 0.f, 0.f, 0.f, 0.f};
    for (int e = beg; e < end; e += 8) {
        uint4 p[8];
        #pragma unroll
        for (int j = 0; j < 8; j++) {
            int ee = e + j; ee = (ee < end - 1) ? ee : end - 1;
            p[j] = h2[(size_t)(sorted[ee] & 0xFFFFu) * 8 + l];
        }
        #pragma unroll
        for (int j = 0; j < 8; j++)
            if (e + j < end) {
                a[0] += bflo(p[j].x); a[1] += bfhi(p[j].x);
                a[2] += bflo(p[j].y); a[3] += bfhi(p[j].y);
                a[4] += bflo(p[j].z); a[5] += bfhi(p[j].z);
                a[6] += bflo(p[j].w); a[7] += bfhi(p[j].w);
            }
    }
    int dI = end - beg; if (dI < 1) dI = 1;
    float r = rsqrtf((float)dI);
    float v[8];
    #pragma unroll
    for (int f = 0; f < 8; f++) v[f] = a[f] * r + b2[8 * l + f];
    float4 oA = {v[0], v[1], v[2], v[3]};
    float4 oB = {v[4], v[5], v[6], v[7]};
    ((float4*)hidden)[(size_t)node * 16 + 2 * l + 0] = oA;
    ((float4*)hidden)[(size_t)node * 16 + 2 * l + 1] = oB;
    float l0 = 0.f, l1 = 0.f;
    #pragma unroll
    for (int f = 0; f < 8; f++) {
        l0 += v[f] * Wf[(8 * l + f) * 2 + 0];
        l1 += v[f] * Wf[(8 * l + f) * 2 + 1];
    }
    #pragma unroll
    for (int off = 4; off > 0; off >>= 1) {
        l0 += __shfl_down(l0, off, 8);
        l1 += __shfl_down(l1, off, 8);
    }
    if (l == 0) {
        logits[(size_t)node * 2 + 0] = l0 + bfv[0];
        logits[(size_t)node * 2 + 1] = l1 + bfv[1];
    }
}

extern "C" void kernel_launch(void* const* d_in, const int* in_sizes, int n_in,
                              void* d_out, int out_size, void* d_ws, size_t ws_size,
                              hipStream_t stream) {
    const float* x   = (const float*)d_in[0];
    const float* W1  = (const float*)d_in[1];
    const float* b1  = (const float*)d_in[2];
    const float* W2  = (const float*)d_in[3];
    const float* b2  = (const float*)d_in[4];
    const float* Wf  = (const float*)d_in[5];
    const float* bfv = (const float*)d_in[6];
    const int* src = (const int*)d_in[7];
    const int* dst = (const int*)d_in[8];

    float* out_logits = (float*)d_out;
    float* out_hidden = (float*)d_out + 2 * NNODES;

    char* ws = (char*)d_ws;
    size_t off = 0;
    auto alloc = [&](size_t bytes) { void* p = ws + off; off += (bytes + 255) & ~(size_t)255; return p; };
    u16*   gh1     = (u16*)alloc(NCH * NCH * 2);
    int*   part1   = (int*)alloc(256 * 4);
    u32*   sbuf    = (u32*)alloc((size_t)NEDGES * 4);
    u32*   sorted  = (u32*)alloc((size_t)NEDGES * 4);
    u32*   histS   = (u32*)alloc((size_t)SHB * 12500 * 4);
    u32*   histD   = (u32*)alloc((size_t)SHB * 12500 * 4);
    int*   deg     = (int*)alloc(2 * NNODES * 4);
    int*   row_ptr = (int*)alloc((NNODES + 1) * 4);
    int*   gdh     = (int*)alloc(PBN * 64 * 4);
    int*   perm    = (int*)alloc(NNODES * 4);
    u16*   Wp1     = (u16*)alloc(256 * 128 * 2);
    u16*   Wp2     = (u16*)alloc(128 * 64 * 2);
    u16*   h       = (u16*)alloc((size_t)NNODES * 128 * 2);
    u16*   h2      = (u16*)alloc((size_t)NNODES * 64 * 2);

    int* deg_out = deg;
    int* deg_in  = deg + NNODES;

    // --- cooperative mega-kernel path ---
    static int grid_cached = -1;
    if (grid_cached < 0) {
        int occ = 0;
        if (hipOccupancyMaxActiveBlocksPerMultiprocessor(&occ, mega, 256, 0) == hipSuccess && occ > 0) {
            static int nCU = 0;
            if (!nCU) { hipDeviceProp_t p; if (hipGetDeviceProperties(&p, 0) == hipSuccess) nCU = p.multiProcessorCount; }
            if (!nCU) nCU = 256;
            long g = (long)occ * nCU;
            if (g > 4096) g = 4096;
            grid_cached = (int)g;
        } else {
            grid_cached = 0;               // cooperative unusable
        }
    }

    bool coop_ok = false;
    if (grid_cached > 0) {
        void* args[] = {
            (void*)&W1, (void*)&W2, (void*)&b1, (void*)&b2, (void*)&Wf, (void*)&bfv,
            (void*)&x, (void*)&src, (void*)&dst,
            (void*)&Wp1, (void*)&Wp2, (void*)&histS, (void*)&histD, (void*)&gh1,
            (void*)&deg_out, (void*)&deg_in, (void*)&gdh, (void*)&part1,
            (void*)&sbuf, (void*)&sorted, (void*)&row_ptr, (void*)&perm,
            (void*)&h, (void*)&h2, (void*)&out_logits, (void*)&out_hidden
        };
        hipError_t e = hipLaunchCooperativeKernel((const void*)mega, dim3(grid_cached), dim3(256),
                                                  args, 0, stream);
        coop_ok = (e == hipSuccess);
        if (!coop_ok) grid_cached = 0;     // don't retry next iterations
    }

    if (!coop_ok) {
        // fallback: round-5 verified 5-launch pipeline
        pre_kernel<<<2 * SHB + NCH + 128, 256, 0, stream>>>(W1, W2, Wp1, Wp2, src, dst, histS, histD, gh1, NEDGES);
        scat_deg<<<NCH, 256, 0, stream>>>(src, dst, gh1, histS, histD, deg_out, deg_in, gdh, part1, sbuf, NEDGES);
        sort_gemm<<<NBUCK + GB1 + PBN, 256, 0, stream>>>(sbuf, part1, sorted, row_ptr, x, Wp1,
                                                         deg_out, deg_in, gdh, perm, h, NEDGES);
        gather1f<<<NNODES / 16, 256, 0, stream>>>((const uint4*)h, row_ptr, sorted, b1, perm, deg_out, Wp2, h2);
        gather2<<<(NNODES * 8 + 255) / 256, 256, 0, stream>>>((const uint4*)h2, row_ptr, sorted, b2, Wf, bfv,
                                                              perm, out_logits, out_hidden, NNODES);
    }
}

// Round 7
// 237.975 us; speedup vs baseline: 2.2589x; 2.2589x over previous
//
#include <hip/hip_runtime.h>
#include <hip/hip_bf16.h>
#include <cstdint>
#include <cstddef>

#define NNODES 50000
#define NEDGES 800000
#define NCH    256
#define CHUNK1 3136                        // 255*3136 + 320 = 800000; every base 16B-aligned
#define NBUCK  196
#define GB1    782
#define SHB    64                          // degree-hist blocks per array
#define SHE    12500                       // 64*12500 = 800000
#define SHEV   (SHE / 1024)                // 12 full uint4 rounds
#define PBN    256
#define PBR    196
#define GGB    782                         // gather blocks: ceil(50000/64)

typedef unsigned short u16;
typedef unsigned int u32;
typedef short bfrag8 __attribute__((ext_vector_type(8)));
typedef float f32x4 __attribute__((ext_vector_type(4)));

__device__ __forceinline__ u16 f2bf(float f) {
    union { float f; uint32_t i; } v; v.f = f;
    uint32_t r = (v.i + 0x7FFFu + ((v.i >> 16) & 1u)) >> 16;
    return (u16)r;
}
__device__ __forceinline__ float bflo(u32 p) { union { uint32_t i; float f; } v; v.i = p << 16; return v.f; }
__device__ __forceinline__ float bfhi(u32 p) { union { uint32_t i; float f; } v; v.i = p & 0xFFFF0000u; return v.f; }

// ===== launch 1: u8-packed degree hists (0..127, uint4 loads) | partition hist (128..383, uint4) | weight prep =====
__global__ __launch_bounds__(256) void pre_kernel(const float* __restrict__ W1, const float* __restrict__ W2,
                                                  u16* __restrict__ P1, u16* __restrict__ P2,
                                                  const int* __restrict__ src, const int* __restrict__ dst,
                                                  u32* __restrict__ histS, u32* __restrict__ histD,
                                                  u16* __restrict__ gh1, int nE) {
    __shared__ u32 hh[12500];              // 50 KB
    int b = blockIdx.x, t = threadIdx.x;
    if (b < 2 * SHB) {
        const int* col = (b < SHB) ? src : dst;
        int bb = (b < SHB) ? b : b - SHB;
        for (int j = t; j < 12500; j += 256) hh[j] = 0;
        __syncthreads();
        int beg = bb * SHE;
        const uint4* col4 = (const uint4*)(col + beg);
        #pragma unroll 4
        for (int k = 0; k < SHEV; k++) {
            uint4 e = col4[k * 256 + t];
            atomicAdd(&hh[e.x >> 2], 1u << ((e.x & 3) * 8));
            atomicAdd(&hh[e.y >> 2], 1u << ((e.y & 3) * 8));
            atomicAdd(&hh[e.z >> 2], 1u << ((e.z & 3) * 8));
            atomicAdd(&hh[e.w >> 2], 1u << ((e.w & 3) * 8));
        }
        for (int i = beg + SHEV * 1024 + t; i < beg + SHE; i += 256) {
            u32 n = (u32)col[i];
            atomicAdd(&hh[n >> 2], 1u << ((n & 3) * 8));
        }
        __syncthreads();
        u32* out = ((b < SHB) ? histS : histD) + (size_t)bb * 12500;
        for (int j = t; j < 12500; j += 256) out[j] = hh[j];
    } else if (b < 2 * SHB + NCH) {
        int c = b - 2 * SHB;
        hh[t] = 0;
        __syncthreads();
        int beg = c * CHUNK1, end = min(beg + CHUNK1, nE);
        const uint4* d4 = (const uint4*)(dst + beg);
        int n4 = (end - beg) >> 2;
        for (int k = t; k < n4; k += 256) {
            uint4 e = d4[k];
            atomicAdd(&hh[e.x >> 8], 1u);
            atomicAdd(&hh[e.y >> 8], 1u);
            atomicAdd(&hh[e.z >> 8], 1u);
            atomicAdd(&hh[e.w >> 8], 1u);
        }
        __syncthreads();
        gh1[c * NCH + t] = (u16)hh[t];     // [chunk][digit]
    } else {
        int i = (b - 2 * SHB - NCH) * 256 + t;
        if (i < 256 * 128) {
            int k = i >> 7, n = i & 127;
            P1[((((k >> 3) << 7) + n) << 3) | (k & 7)] = f2bf(W1[i]);
        }
        if (i < 128 * 64) {
            int k = i >> 6, n = i & 63;
            P2[((((k >> 3) << 6) + n) << 3) | (k & 7)] = f2bf(W2[i]);
        }
    }
}

// ===== launch 2: partition scatter + deg reduce + gdh (grid = 256) =====
__global__ __launch_bounds__(256) void scat_deg(const int* __restrict__ src, const int* __restrict__ dst,
                                                const u16* __restrict__ gh1,
                                                const u32* __restrict__ histS, const u32* __restrict__ histD,
                                                int* __restrict__ deg_out, int* __restrict__ deg_in,
                                                int* __restrict__ gdh, int* __restrict__ part1,
                                                u32* __restrict__ sbuf, int nE) {
    int t = threadIdx.x, c = blockIdx.x;
    __shared__ int sd[256];
    __shared__ u32 base[256];
    __shared__ u32 lh[256];
    __shared__ int cnt64[64];
    if (t < 64) cnt64[t] = 0;
    int tot = 0, par = 0;
    #pragma unroll 8
    for (int cc = 0; cc < NCH; cc++) {
        int v = (int)gh1[cc * NCH + t];
        tot += v;
        par += (cc < c) ? v : 0;
    }
    if (c == 0) part1[t] = tot;
    sd[t] = tot;
    __syncthreads();
    #pragma unroll
    for (int o = 1; o < 256; o <<= 1) {
        int add = (t >= o) ? sd[t - o] : 0;
        __syncthreads();
        sd[t] += add;
        __syncthreads();
    }
    base[t] = (u32)((sd[t] - tot) + par);
    lh[t] = 0;
    __syncthreads();
    int beg = c * CHUNK1, end = min(beg + CHUNK1, nE);
    const uint4* s4 = (const uint4*)(src + beg);
    const uint4* d4 = (const uint4*)(dst + beg);
    int n4 = (end - beg) >> 2;
    for (int k = t; k < n4; k += 256) {
        uint4 es = s4[k], ed = d4[k];
        u32 el, dg, r;
        el = (ed.x << 16) | es.x; dg = el >> 24; r = atomicAdd(&lh[dg], 1); sbuf[base[dg] + r] = el;
        el = (ed.y << 16) | es.y; dg = el >> 24; r = atomicAdd(&lh[dg], 1); sbuf[base[dg] + r] = el;
        el = (ed.z << 16) | es.z; dg = el >> 24; r = atomicAdd(&lh[dg], 1); sbuf[base[dg] + r] = el;
        el = (ed.w << 16) | es.w; dg = el >> 24; r = atomicAdd(&lh[dg], 1); sbuf[base[dg] + r] = el;
    }
    int n = c * PBR + t;
    if (t < PBR && n < NNODES) {
        int w = n >> 2, sh = (n & 3) * 8;
        int so = 0, si = 0;
        #pragma unroll 8
        for (int r = 0; r < SHB; r++) {
            so += (int)((histS[(size_t)r * 12500 + w] >> sh) & 255u);
            si += (int)((histD[(size_t)r * 12500 + w] >> sh) & 255u);
        }
        deg_out[n] = so;
        deg_in[n] = si;
        atomicAdd(&cnt64[si > 63 ? 63 : si], 1);
    }
    __syncthreads();
    if (t < 64) gdh[c * 64 + t] = cnt64[t];
}

// ============ dense gemm body — output in 32-feature-group-major layout ============
// out[((f>>5)*M + row)*32 + (f&31)]  (f = output feature). Same values as node-major,
// but each 32-feature group is a physically separate 3.2 MB table -> per-XCD L2-resident
// for the feature-split gathers. Write coalescing unchanged (16 contiguous u16 per wave/t).
template <int K, int N, bool AF32>
__device__ __forceinline__ void gemm_body(const void* __restrict__ A_, const u16* __restrict__ Wp,
                                          const int* __restrict__ deg, u16* __restrict__ out, int M, int bx) {
    const int lane = threadIdx.x & 63;
    const int wave = threadIdx.x >> 6;
    const int m = lane & 15;
    const int q = lane >> 4;
    const int row0 = bx * 64 + wave * 16;
    int rowa = row0 + m; if (rowa > M - 1) rowa = M - 1;
    constexpr int NT = N / 16;
    f32x4 acc[NT];
    #pragma unroll
    for (int t = 0; t < NT; t++) acc[t] = (f32x4){0.f, 0.f, 0.f, 0.f};
    #pragma unroll
    for (int kc = 0; kc < K; kc += 32) {
        bfrag8 af;
        if constexpr (AF32) {
            const float* ap = (const float*)A_ + (size_t)rowa * K + q * 8 + kc;
            const float4 x0 = *(const float4*)(ap);
            const float4 x1 = *(const float4*)(ap + 4);
            af[0] = (short)f2bf(x0.x); af[1] = (short)f2bf(x0.y);
            af[2] = (short)f2bf(x0.z); af[3] = (short)f2bf(x0.w);
            af[4] = (short)f2bf(x1.x); af[5] = (short)f2bf(x1.y);
            af[6] = (short)f2bf(x1.z); af[7] = (short)f2bf(x1.w);
        } else {
            const u16* ap = (const u16*)A_ + (size_t)rowa * K + q * 8 + kc;
            af = *(const bfrag8*)ap;
        }
        const u16* bbase = Wp + ((size_t)(((kc >> 3) + q) * N) + m) * 8;
        #pragma unroll
        for (int t = 0; t < NT; t++) {
            bfrag8 bf_ = *(const bfrag8*)(bbase + t * 128);
            acc[t] = __builtin_amdgcn_mfma_f32_16x16x32_bf16(af, bf_, acc[t], 0, 0, 0);
        }
    }
    #pragma unroll
    for (int r = 0; r < 4; r++) {
        int gr = row0 + q * 4 + r;
        if (gr < M) {
            int dO = deg[gr]; if (dO < 1) dO = 1;
            float s = rsqrtf((float)dO);
            #pragma unroll
            for (int t = 0; t < NT; t++) {
                int f = t * 16 + m;
                out[((size_t)(f >> 5) * M + gr) * 32 + (f & 31)] = f2bf(acc[t][r] * s);
            }
        }
    }
}

template <int K, int N, bool AF32>
__global__ __launch_bounds__(256) void gemm_scaled(const void* __restrict__ A_, const u16* __restrict__ Wp,
                                                   const int* __restrict__ deg, u16* __restrict__ out, int M) {
    gemm_body<K, N, AF32>(A_, Wp, deg, out, M, blockIdx.x);
}

// ===== launch 3: per-bucket counting sort + row_ptr (0..195) | layer-1 gemm (196..977) | perm (978..1233) =====
__global__ __launch_bounds__(256) void sort_gemm(const u32* __restrict__ sbuf, const int* __restrict__ part1,
                                                 u32* __restrict__ sorted, int* __restrict__ rp,
                                                 const float* __restrict__ x, const u16* __restrict__ Wp1,
                                                 const int* __restrict__ deg_out, const int* __restrict__ deg_in,
                                                 const int* __restrict__ gdh, int* __restrict__ perm,
                                                 u16* __restrict__ h, int nE) {
    int b = blockIdx.x, t = threadIdx.x;
    if (b < NBUCK) {
        __shared__ int sd[256];
        __shared__ int cnt[256];
        __shared__ int cursor[256];
        int v = part1[t];
        sd[t] = v;
        __syncthreads();
        #pragma unroll
        for (int o = 1; o < 256; o <<= 1) {
            int add = (t >= o) ? sd[t - o] : 0;
            __syncthreads();
            sd[t] += add;
            __syncthreads();
        }
        __shared__ int bs_s, bl_s;
        if (t == b) { bs_s = sd[t] - v; bl_s = v; }
        __syncthreads();
        int bstart = bs_s, bend = bstart + bl_s;
        cnt[t] = 0;
        __syncthreads();
        for (int i = bstart + t; i < bend; i += 256)
            atomicAdd(&cnt[(sbuf[i] >> 16) & 255u], 1);
        __syncthreads();
        int cv = cnt[t];
        sd[t] = cv;
        __syncthreads();
        #pragma unroll
        for (int o = 1; o < 256; o <<= 1) {
            int add = (t >= o) ? sd[t - o] : 0;
            __syncthreads();
            sd[t] += add;
            __syncthreads();
        }
        int excl = sd[t] - cv;
        int node = b * 256 + t;
        if (node < NNODES) rp[node] = bstart + excl;
        if (b == NBUCK - 1 && t == 0) rp[NNODES] = nE;
        cursor[t] = excl;
        __syncthreads();
        for (int i = bstart + t; i < bend; i += 256) {
            u32 el = sbuf[i];
            int r = atomicAdd(&cursor[(el >> 16) & 255u], 1);
            sorted[bstart + r] = el;
        }
    } else if (b < NBUCK + GB1) {
        gemm_body<256, 128, true>(x, Wp1, deg_out, h, NNODES, b - NBUCK);
    } else {
        int pb = b - NBUCK - GB1;
        __shared__ int cse[64];
        __shared__ int cur[64];
        if (t < 64) {
            int s_all = 0, s_pre = 0;
            for (int q2 = 0; q2 < PBN; q2++) {
                int v = gdh[q2 * 64 + t];
                s_all += v;
                s_pre += (q2 < pb) ? v : 0;
            }
            cse[t] = s_all;
            cur[t] = s_pre;
        }
        __syncthreads();
        if (t == 0) {
            int s = 0;
            for (int d2 = 0; d2 < 64; d2++) { int v = cse[d2]; cse[d2] = s; s += v; }
        }
        __syncthreads();
        if (t < 64) cur[t] += cse[t];
        __syncthreads();
        int n = pb * PBR + t;
        if (t < PBR && n < NNODES) {
            int d = deg_in[n]; d = d > 63 ? 63 : d;
            int p = atomicAdd(&cur[d], 1);
            perm[p] = n;
        }
    }
}

// ===== launches 4-7: layer-1 gather, one 32-feature quarter per launch (3.2 MB table, L2-resident) =====
// 4 lanes x 16B per node, 64 nodes/block, degree-balanced via perm. Edge-sum order identical to the
// fused gather (same e-loop, same unroll) -> bit-identical h1.
__global__ __launch_bounds__(256) void gather1q(const uint4* __restrict__ hq, const int* __restrict__ row_ptr,
                                                const u32* __restrict__ sorted, const float* __restrict__ b1,
                                                const int* __restrict__ perm, uint4* __restrict__ h1out,
                                                int qtr) {
    int g = blockIdx.x * 64 + (threadIdx.x >> 2);
    int l = threadIdx.x & 3;
    if (g >= NNODES) return;
    int node = perm[g];
    int beg = row_ptr[node], end = row_ptr[node + 1];
    const uint4* tbl = hq + (size_t)qtr * NNODES * 4;
    float a[8] = {0.f, 0.f, 0.f, 0.f, 0.f, 0.f, 0.f, 0.f};
    for (int e = beg; e < end; e += 8) {
        uint4 p[8];
        #pragma unroll
        for (int j = 0; j < 8; j++) {
            int ee = e + j; ee = (ee < end - 1) ? ee : end - 1;
            p[j] = tbl[(size_t)(sorted[ee] & 0xFFFFu) * 4 + l];
        }
        #pragma unroll
        for (int j = 0; j < 8; j++)
            if (e + j < end) {
                a[0] += bflo(p[j].x); a[1] += bfhi(p[j].x);
                a[2] += bflo(p[j].y); a[3] += bfhi(p[j].y);
                a[4] += bflo(p[j].z); a[5] += bfhi(p[j].z);
                a[6] += bflo(p[j].w); a[7] += bfhi(p[j].w);
            }
    }
    int dI = end - beg; if (dI < 1) dI = 1;
    float r = rsqrtf((float)dI);
    const float4 bA = *(const float4*)(b1 + qtr * 32 + l * 8);
    const float4 bB = *(const float4*)(b1 + qtr * 32 + l * 8 + 4);
    float v0 = fmaxf(a[0] * r + bA.x, 0.f), v1 = fmaxf(a[1] * r + bA.y, 0.f);
    float v2 = fmaxf(a[2] * r + bA.z, 0.f), v3 = fmaxf(a[3] * r + bA.w, 0.f);
    float v4 = fmaxf(a[4] * r + bB.x, 0.f), v5 = fmaxf(a[5] * r + bB.y, 0.f);
    float v6 = fmaxf(a[6] * r + bB.z, 0.f), v7 = fmaxf(a[7] * r + bB.w, 0.f);
    uint4 o;
    o.x = ((u32)f2bf(v1) << 16) | f2bf(v0);
    o.y = ((u32)f2bf(v3) << 16) | f2bf(v2);
    o.z = ((u32)f2bf(v5) << 16) | f2bf(v4);
    o.w = ((u32)f2bf(v7) << 16) | f2bf(v6);
    h1out[(size_t)node * 16 + qtr * 4 + l] = o;   // h1 node-major (streamed once by gemm2)
}

// ===== launches 9-10: layer-2 gather + projection, one 32-feature half per launch (3.2 MB table) =====
// half 0 stores partial logits to lpart; half 1 (launch-ordered after) adds its partial + bias.
__global__ __launch_bounds__(256) void gather2h(const uint4* __restrict__ h2h, const int* __restrict__ row_ptr,
                                                const u32* __restrict__ sorted, const float* __restrict__ b2,
                                                const float* __restrict__ Wf, const float* __restrict__ bfv,
                                                const int* __restrict__ perm, float* __restrict__ lpart,
                                                float* __restrict__ logits, float* __restrict__ hidden,
                                                int half) {
    int g = blockIdx.x * 64 + (threadIdx.x >> 2);
    int l = threadIdx.x & 3;
    if (g >= NNODES) return;
    int node = perm[g];
    int beg = row_ptr[node], end = row_ptr[node + 1];
    const uint4* tbl = h2h + (size_t)half * NNODES * 4;
    float a[8] = {0.f, 0.f, 0.f, 0.f, 0.f, 0.f, 0.f, 0.f};
    for (int e = beg; e < end; e += 8) {
        uint4 p[8];
        #pragma unroll
        for (int j = 0; j < 8; j++) {
            int ee = e + j; ee = (ee < end - 1) ? ee : end - 1;
            p[j] = tbl[(size_t)(sorted[ee] & 0xFFFFu) * 4 + l];
        }
        #pragma unroll
        for (int j = 0; j < 8; j++)
            if (e + j < end) {
                a[0] += bflo(p[j].x); a[1] += bfhi(p[j].x);
                a[2] += bflo(p[j].y); a[3] += bfhi(p[j].y);
                a[4] += bflo(p[j].z); a[5] += bfhi(p[j].z);
                a[6] += bflo(p[j].w); a[7] += bfhi(p[j].w);
            }
    }
    int dI = end - beg; if (dI < 1) dI = 1;
    float r = rsqrtf((float)dI);
    int fb = half * 32 + l * 8;
    float v[8];
    #pragma unroll
    for (int f = 0; f < 8; f++) v[f] = a[f] * r + b2[fb + f];
    float4 oA = {v[0], v[1], v[2], v[3]};
    float4 oB = {v[4], v[5], v[6], v[7]};
    ((float4*)hidden)[(size_t)node * 16 + half * 8 + l * 2 + 0] = oA;
    ((float4*)hidden)[(size_t)node * 16 + half * 8 + l * 2 + 1] = oB;
    float l0 = 0.f, l1 = 0.f;
    #pragma unroll
    for (int f = 0; f < 8; f++) {
        l0 += v[f] * Wf[(fb + f) * 2 + 0];
        l1 += v[f] * Wf[(fb + f) * 2 + 1];
    }
    l0 += __shfl_down(l0, 2, 4); l0 += __shfl_down(l0, 1, 4);
    l1 += __shfl_down(l1, 2, 4); l1 += __shfl_down(l1, 1, 4);
    if (l == 0) {
        if (half == 0) {
            lpart[(size_t)node * 2 + 0] = l0;
            lpart[(size_t)node * 2 + 1] = l1;
        } else {
            logits[(size_t)node * 2 + 0] = lpart[(size_t)node * 2 + 0] + l0 + bfv[0];
            logits[(size_t)node * 2 + 1] = lpart[(size_t)node * 2 + 1] + l1 + bfv[1];
        }
    }
}

extern "C" void kernel_launch(void* const* d_in, const int* in_sizes, int n_in,
                              void* d_out, int out_size, void* d_ws, size_t ws_size,
                              hipStream_t stream) {
    const float* x   = (const float*)d_in[0];
    const float* W1  = (const float*)d_in[1];
    const float* b1  = (const float*)d_in[2];
    const float* W2  = (const float*)d_in[3];
    const float* b2  = (const float*)d_in[4];
    const float* Wf  = (const float*)d_in[5];
    const float* bfv = (const float*)d_in[6];
    const int* src = (const int*)d_in[7];
    const int* dst = (const int*)d_in[8];

    float* out_logits = (float*)d_out;
    float* out_hidden = (float*)d_out + 2 * NNODES;

    char* ws = (char*)d_ws;
    size_t off = 0;
    auto alloc = [&](size_t bytes) { void* p = ws + off; off += (bytes + 255) & ~(size_t)255; return p; };
    u16*   gh1     = (u16*)alloc(NCH * NCH * 2);            // 128 KB [chunk][digit]
    int*   part1   = (int*)alloc(256 * 4);
    u32*   sbuf    = (u32*)alloc((size_t)NEDGES * 4);
    u32*   sorted  = (u32*)alloc((size_t)NEDGES * 4);
    u32*   histS   = (u32*)alloc((size_t)SHB * 12500 * 4);  // 3.2 MB u8-packed partials
    u32*   histD   = (u32*)alloc((size_t)SHB * 12500 * 4);  // 3.2 MB
    int*   deg     = (int*)alloc(2 * NNODES * 4);
    int*   row_ptr = (int*)alloc((NNODES + 1) * 4);
    int*   gdh     = (int*)alloc(PBN * 64 * 4);
    int*   perm    = (int*)alloc(NNODES * 4);
    u16*   Wp1     = (u16*)alloc(256 * 128 * 2);
    u16*   Wp2     = (u16*)alloc(128 * 64 * 2);
    u16*   h       = (u16*)alloc((size_t)NNODES * 128 * 2); // 12.8 MB, 4x 3.2MB quarter tables
    u16*   h1      = (u16*)alloc((size_t)NNODES * 128 * 2); // 12.8 MB node-major intermediate
    u16*   h2      = (u16*)alloc((size_t)NNODES * 64 * 2);  // 6.4 MB, 2x 3.2MB half tables
    float* lpart   = (float*)alloc((size_t)NNODES * 2 * 4); // 400 KB partial logits

    int* deg_out = deg;
    int* deg_in  = deg + NNODES;

    // 1: u8 degree hists + partition hist (dst>>8) + weight prep
    pre_kernel<<<2 * SHB + NCH + 128, 256, 0, stream>>>(W1, W2, Wp1, Wp2, src, dst, histS, histD, gh1, NEDGES);
    // 2: partition scatter + deg reduce + gdh
    scat_deg<<<NCH, 256, 0, stream>>>(src, dst, gh1, histS, histD, deg_out, deg_in, gdh, part1, sbuf, NEDGES);
    // 3: bucket sort + row_ptr || layer-1 gemm (h in quarter-major) || perm scatter
    sort_gemm<<<NBUCK + GB1 + PBN, 256, 0, stream>>>(sbuf, part1, sorted, row_ptr, x, Wp1,
                                                     deg_out, deg_in, gdh, perm, h, NEDGES);
    // 4-7: layer-1 gather, one L2-resident quarter table per launch (serialized by the stream)
    for (int q = 0; q < 4; q++)
        gather1q<<<GGB, 256, 0, stream>>>((const uint4*)h, row_ptr, sorted, b1, perm, (uint4*)h1, q);
    // 8: layer-2 gemm: h1 -> h2 (half-major)
    gemm_scaled<128, 64, false><<<GB1, 256, 0, stream>>>(h1, Wp2, deg_out, h2, NNODES);
    // 9-10: layer-2 gather + projection, one L2-resident half table per launch
    gather2h<<<GGB, 256, 0, stream>>>((const uint4*)h2, row_ptr, sorted, b2, Wf, bfv, perm,
                                      lpart, out_logits, out_hidden, 0);
    gather2h<<<GGB, 256, 0, stream>>>((const uint4*)h2, row_ptr, sorted, b2, Wf, bfv, perm,
                                      lpart, out_logits, out_hidden, 1);
}

// Round 8
// 192.012 us; speedup vs baseline: 2.7996x; 1.2394x over previous
//
#include <hip/hip_runtime.h>
#include <hip/hip_bf16.h>
#include <cstdint>
#include <cstddef>

#define NNODES 50000
#define NEDGES 800000
// pass-1 partition by dst>>8: 256 chunks x 3136 edges (16B-aligned bases), 256 digit rows (196 used)
#define NCH    256
#define CHUNK1 3136                        // 255*3136 + 320 = 800000; every base 16B-aligned
#define NBUCK  196                         // ceil(50000/256)
#define GB1    782                         // ceil(50000/64) gemm blocks
#define SHB    64                          // degree-hist blocks per array (src, dst)
#define SHE    12500                       // 64*12500 = 800000 exact
#define SHEV   (SHE / 1024)                // 12 full uint4 rounds
#define PBN    256                         // perm blocks
#define PBR    196                         // nodes per perm block

typedef unsigned short u16;
typedef unsigned int u32;
typedef short bfrag8 __attribute__((ext_vector_type(8)));
typedef float f32x4 __attribute__((ext_vector_type(4)));

__device__ __forceinline__ u16 f2bf(float f) {
    union { float f; uint32_t i; } v; v.f = f;
    uint32_t r = (v.i + 0x7FFFu + ((v.i >> 16) & 1u)) >> 16;
    return (u16)r;
}
__device__ __forceinline__ float bflo(u32 p) { union { uint32_t i; float f; } v; v.i = p << 16; return v.f; }
__device__ __forceinline__ float bfhi(u32 p) { union { uint32_t i; float f; } v; v.i = p & 0xFFFF0000u; return v.f; }

// ===== launch 1: u8-packed degree hists (0..127, uint4 loads) | partition hist (128..383, uint4) | weight prep =====
__global__ __launch_bounds__(256) void pre_kernel(const float* __restrict__ W1, const float* __restrict__ W2,
                                                  u16* __restrict__ P1, u16* __restrict__ P2,
                                                  const int* __restrict__ src, const int* __restrict__ dst,
                                                  u32* __restrict__ histS, u32* __restrict__ histD,
                                                  u16* __restrict__ gh1, int nE) {
    __shared__ u32 hh[12500];              // 50 KB
    int b = blockIdx.x, t = threadIdx.x;
    if (b < 2 * SHB) {
        const int* col = (b < SHB) ? src : dst;
        int bb = (b < SHB) ? b : b - SHB;
        for (int j = t; j < 12500; j += 256) hh[j] = 0;
        __syncthreads();
        int beg = bb * SHE;
        const uint4* col4 = (const uint4*)(col + beg);
        #pragma unroll 4
        for (int k = 0; k < SHEV; k++) {
            uint4 e = col4[k * 256 + t];
            atomicAdd(&hh[e.x >> 2], 1u << ((e.x & 3) * 8));
            atomicAdd(&hh[e.y >> 2], 1u << ((e.y & 3) * 8));
            atomicAdd(&hh[e.z >> 2], 1u << ((e.z & 3) * 8));
            atomicAdd(&hh[e.w >> 2], 1u << ((e.w & 3) * 8));
        }
        for (int i = beg + SHEV * 1024 + t; i < beg + SHE; i += 256) {
            u32 n = (u32)col[i];
            atomicAdd(&hh[n >> 2], 1u << ((n & 3) * 8));
        }
        __syncthreads();
        u32* out = ((b < SHB) ? histS : histD) + (size_t)bb * 12500;
        for (int j = t; j < 12500; j += 256) out[j] = hh[j];
    } else if (b < 2 * SHB + NCH) {
        int c = b - 2 * SHB;
        hh[t] = 0;
        __syncthreads();
        int beg = c * CHUNK1, end = min(beg + CHUNK1, nE);
        const uint4* d4 = (const uint4*)(dst + beg);
        int n4 = (end - beg) >> 2;
        for (int k = t; k < n4; k += 256) {
            uint4 e = d4[k];
            atomicAdd(&hh[e.x >> 8], 1u);
            atomicAdd(&hh[e.y >> 8], 1u);
            atomicAdd(&hh[e.z >> 8], 1u);
            atomicAdd(&hh[e.w >> 8], 1u);
        }
        __syncthreads();
        gh1[c * NCH + t] = (u16)hh[t];     // [chunk][digit]
    } else {
        int i = (b - 2 * SHB - NCH) * 256 + t;
        if (i < 256 * 128) {
            int k = i >> 7, n = i & 127;
            P1[((((k >> 3) << 7) + n) << 3) | (k & 7)] = f2bf(W1[i]);
        }
        if (i < 128 * 64) {
            int k = i >> 6, n = i & 63;
            P2[((((k >> 3) << 6) + n) << 3) | (k & 7)] = f2bf(W2[i]);
        }
    }
}

// ===== launch 2: partition scatter + deg reduce + gdh (grid = 256) =====
__global__ __launch_bounds__(256) void scat_deg(const int* __restrict__ src, const int* __restrict__ dst,
                                                const u16* __restrict__ gh1,
                                                const u32* __restrict__ histS, const u32* __restrict__ histD,
                                                int* __restrict__ deg_out, int* __restrict__ deg_in,
                                                int* __restrict__ gdh, int* __restrict__ part1,
                                                u32* __restrict__ sbuf, int nE) {
    int t = threadIdx.x, c = blockIdx.x;
    __shared__ int sd[256];
    __shared__ u32 base[256];
    __shared__ u32 lh[256];
    __shared__ int cnt64[64];
    if (t < 64) cnt64[t] = 0;
    int tot = 0, par = 0;
    #pragma unroll 8
    for (int cc = 0; cc < NCH; cc++) {
        int v = (int)gh1[cc * NCH + t];
        tot += v;
        par += (cc < c) ? v : 0;
    }
    if (c == 0) part1[t] = tot;
    sd[t] = tot;
    __syncthreads();
    #pragma unroll
    for (int o = 1; o < 256; o <<= 1) {
        int add = (t >= o) ? sd[t - o] : 0;
        __syncthreads();
        sd[t] += add;
        __syncthreads();
    }
    base[t] = (u32)((sd[t] - tot) + par);
    lh[t] = 0;
    __syncthreads();
    int beg = c * CHUNK1, end = min(beg + CHUNK1, nE);
    const uint4* s4 = (const uint4*)(src + beg);
    const uint4* d4 = (const uint4*)(dst + beg);
    int n4 = (end - beg) >> 2;
    for (int k = t; k < n4; k += 256) {
        uint4 es = s4[k], ed = d4[k];
        u32 el, dg, r;
        el = (ed.x << 16) | es.x; dg = el >> 24; r = atomicAdd(&lh[dg], 1); sbuf[base[dg] + r] = el;
        el = (ed.y << 16) | es.y; dg = el >> 24; r = atomicAdd(&lh[dg], 1); sbuf[base[dg] + r] = el;
        el = (ed.z << 16) | es.z; dg = el >> 24; r = atomicAdd(&lh[dg], 1); sbuf[base[dg] + r] = el;
        el = (ed.w << 16) | es.w; dg = el >> 24; r = atomicAdd(&lh[dg], 1); sbuf[base[dg] + r] = el;
    }
    int n = c * PBR + t;
    if (t < PBR && n < NNODES) {
        int w = n >> 2, sh = (n & 3) * 8;
        int so = 0, si = 0;
        #pragma unroll 8
        for (int r = 0; r < SHB; r++) {
            so += (int)((histS[(size_t)r * 12500 + w] >> sh) & 255u);
            si += (int)((histD[(size_t)r * 12500 + w] >> sh) & 255u);
        }
        deg_out[n] = so;
        deg_in[n] = si;
        atomicAdd(&cnt64[si > 63 ? 63 : si], 1);
    }
    __syncthreads();
    if (t < 64) gdh[c * 64 + t] = cnt64[t];
}

// ============ dense gemm body (verified r8-r11); h written nontemporal (read-once from L3 next launch) ============
template <int K, int N, bool AF32>
__device__ __forceinline__ void gemm_body(const void* __restrict__ A_, const u16* __restrict__ Wp,
                                          const int* __restrict__ deg, u16* __restrict__ out, int M, int bx) {
    const int lane = threadIdx.x & 63;
    const int wave = threadIdx.x >> 6;
    const int m = lane & 15;
    const int q = lane >> 4;
    const int row0 = bx * 64 + wave * 16;
    int rowa = row0 + m; if (rowa > M - 1) rowa = M - 1;
    constexpr int NT = N / 16;
    f32x4 acc[NT];
    #pragma unroll
    for (int t = 0; t < NT; t++) acc[t] = (f32x4){0.f, 0.f, 0.f, 0.f};
    #pragma unroll
    for (int kc = 0; kc < K; kc += 32) {
        bfrag8 af;
        if constexpr (AF32) {
            const float* ap = (const float*)A_ + (size_t)rowa * K + q * 8 + kc;
            const float4 x0 = *(const float4*)(ap);
            const float4 x1 = *(const float4*)(ap + 4);
            af[0] = (short)f2bf(x0.x); af[1] = (short)f2bf(x0.y);
            af[2] = (short)f2bf(x0.z); af[3] = (short)f2bf(x0.w);
            af[4] = (short)f2bf(x1.x); af[5] = (short)f2bf(x1.y);
            af[6] = (short)f2bf(x1.z); af[7] = (short)f2bf(x1.w);
        } else {
            const u16* ap = (const u16*)A_ + (size_t)rowa * K + q * 8 + kc;
            af = *(const bfrag8*)ap;
        }
        const u16* bbase = Wp + ((size_t)(((kc >> 3) + q) * N) + m) * 8;
        #pragma unroll
        for (int t = 0; t < NT; t++) {
            bfrag8 bf_ = *(const bfrag8*)(bbase + t * 128);
            acc[t] = __builtin_amdgcn_mfma_f32_16x16x32_bf16(af, bf_, acc[t], 0, 0, 0);
        }
    }
    #pragma unroll
    for (int r = 0; r < 4; r++) {
        int gr = row0 + q * 4 + r;
        if (gr < M) {
            int dO = deg[gr]; if (dO < 1) dO = 1;
            float s = rsqrtf((float)dO);
            #pragma unroll
            for (int t = 0; t < NT; t++)
                __builtin_nontemporal_store(f2bf(acc[t][r] * s), &out[(size_t)gr * N + t * 16 + m]);
        }
    }
}

// ===== launch 3: per-bucket counting sort + row_ptr (0..195) | layer-1 gemm (196..977) | perm (978..1233) =====
__global__ __launch_bounds__(256) void sort_gemm(const u32* __restrict__ sbuf, const int* __restrict__ part1,
                                                 u32* __restrict__ sorted, int* __restrict__ rp,
                                                 const float* __restrict__ x, const u16* __restrict__ Wp1,
                                                 const int* __restrict__ deg_out, const int* __restrict__ deg_in,
                                                 const int* __restrict__ gdh, int* __restrict__ perm,
                                                 u16* __restrict__ h, int nE) {
    int b = blockIdx.x, t = threadIdx.x;
    if (b < NBUCK) {
        __shared__ int sd[256];
        __shared__ int cnt[256];
        __shared__ int cursor[256];
        int v = part1[t];
        sd[t] = v;
        __syncthreads();
        #pragma unroll
        for (int o = 1; o < 256; o <<= 1) {
            int add = (t >= o) ? sd[t - o] : 0;
            __syncthreads();
            sd[t] += add;
            __syncthreads();
        }
        __shared__ int bs_s, bl_s;
        if (t == b) { bs_s = sd[t] - v; bl_s = v; }
        __syncthreads();
        int bstart = bs_s, bend = bstart + bl_s;
        cnt[t] = 0;
        __syncthreads();
        for (int i = bstart + t; i < bend; i += 256)
            atomicAdd(&cnt[(sbuf[i] >> 16) & 255u], 1);
        __syncthreads();
        int cv = cnt[t];
        sd[t] = cv;
        __syncthreads();
        #pragma unroll
        for (int o = 1; o < 256; o <<= 1) {
            int add = (t >= o) ? sd[t - o] : 0;
            __syncthreads();
            sd[t] += add;
            __syncthreads();
        }
        int excl = sd[t] - cv;
        int node = b * 256 + t;
        if (node < NNODES) rp[node] = bstart + excl;
        if (b == NBUCK - 1 && t == 0) rp[NNODES] = nE;
        cursor[t] = excl;
        __syncthreads();
        for (int i = bstart + t; i < bend; i += 256) {
            u32 el = sbuf[i];
            int r = atomicAdd(&cursor[(el >> 16) & 255u], 1);
            sorted[bstart + r] = el;
        }
    } else if (b < NBUCK + GB1) {
        gemm_body<256, 128, true>(x, Wp1, deg_out, h, NNODES, b - NBUCK);
    } else {
        int pb = b - NBUCK - GB1;
        __shared__ int cse[64];
        __shared__ int cur[64];
        if (t < 64) {
            int s_all = 0, s_pre = 0;
            for (int q2 = 0; q2 < PBN; q2++) {
                int v = gdh[q2 * 64 + t];
                s_all += v;
                s_pre += (q2 < pb) ? v : 0;
            }
            cse[t] = s_all;
            cur[t] = s_pre;
        }
        __syncthreads();
        if (t == 0) {
            int s = 0;
            for (int d2 = 0; d2 < 64; d2++) { int v = cse[d2]; cse[d2] = s; s += v; }
        }
        __syncthreads();
        if (t < 64) cur[t] += cse[t];
        __syncthreads();
        int n = pb * PBR + t;
        if (t < PBR && n < NNODES) {
            int d = deg_in[n]; d = d > 63 ? 63 : d;
            int p = atomicAdd(&cur[d], 1);
            perm[p] = n;
        }
    }
}

// ---- launch 4: layer-1 gather fused with layer-2 gemm. Sorted-index prefetch double-buffer added:
// next batch's sorted[] loads are issued while the current batch's h-row loads are in flight,
// hiding the index->row two-level latency chain. Values/order bit-identical to round 5.
__global__ __launch_bounds__(256) void gather1f(const uint4* __restrict__ h, const int* __restrict__ row_ptr,
                                                const u32* __restrict__ sorted, const float* __restrict__ b1,
                                                const int* __restrict__ perm, const int* __restrict__ deg_out,
                                                const u16* __restrict__ Wp2, u16* __restrict__ h2) {
    __shared__ __align__(16) u16 sh[16 * 136];
    int t = threadIdx.x;
    int qw = t >> 4;
    int l = t & 15;
    int g = blockIdx.x * 16 + qw;
    int node = perm[g];
    int beg = row_ptr[node], end = row_ptr[node + 1];
    float a[8] = {0.f, 0.f, 0.f, 0.f, 0.f, 0.f, 0.f, 0.f};
    u32 s[8];
    #pragma unroll
    for (int j = 0; j < 8; j++) {
        int ee = beg + j; ee = (ee < end - 1) ? ee : end - 1;
        s[j] = sorted[ee];
    }
    for (int e = beg; e < end; e += 8) {
        int en = e + 8;
        u32 s2[8];
        if (en < end) {
            #pragma unroll
            for (int j = 0; j < 8; j++) {
                int ee = en + j; ee = (ee < end - 1) ? ee : end - 1;
                s2[j] = sorted[ee];
            }
        }
        uint4 p[8];
        #pragma unroll
        for (int j = 0; j < 8; j++)
            p[j] = h[(size_t)(s[j] & 0xFFFFu) * 16 + l];
        #pragma unroll
        for (int j = 0; j < 8; j++)
            if (e + j < end) {
                a[0] += bflo(p[j].x); a[1] += bfhi(p[j].x);
                a[2] += bflo(p[j].y); a[3] += bfhi(p[j].y);
                a[4] += bflo(p[j].z); a[5] += bfhi(p[j].z);
                a[6] += bflo(p[j].w); a[7] += bfhi(p[j].w);
            }
        if (en < end) {
            #pragma unroll
            for (int j = 0; j < 8; j++) s[j] = s2[j];
        }
    }
    int dI = end - beg; if (dI < 1) dI = 1;
    float r = rsqrtf((float)dI);
    const float4 bA = *(const float4*)(b1 + 8 * l);
    const float4 bB = *(const float4*)(b1 + 8 * l + 4);
    float v0 = fmaxf(a[0] * r + bA.x, 0.f), v1 = fmaxf(a[1] * r + bA.y, 0.f);
    float v2 = fmaxf(a[2] * r + bA.z, 0.f), v3 = fmaxf(a[3] * r + bA.w, 0.f);
    float v4 = fmaxf(a[4] * r + bB.x, 0.f), v5 = fmaxf(a[5] * r + bB.y, 0.f);
    float v6 = fmaxf(a[6] * r + bB.z, 0.f), v7 = fmaxf(a[7] * r + bB.w, 0.f);
    uint4 o;
    o.x = ((u32)f2bf(v1) << 16) | f2bf(v0);
    o.y = ((u32)f2bf(v3) << 16) | f2bf(v2);
    o.z = ((u32)f2bf(v5) << 16) | f2bf(v4);
    o.w = ((u32)f2bf(v7) << 16) | f2bf(v6);
    *(uint4*)&sh[qw * 136 + l * 8] = o;
    __syncthreads();
    const int lane = t & 63;
    const int m = lane & 15;
    const int q = lane >> 4;
    const int w = t >> 6;
    f32x4 acc = (f32x4){0.f, 0.f, 0.f, 0.f};
    #pragma unroll
    for (int kc = 0; kc < 128; kc += 32) {
        bfrag8 af = *(const bfrag8*)&sh[m * 136 + q * 8 + kc];
        bfrag8 bf_ = *(const bfrag8*)(Wp2 + ((size_t)(((kc >> 3) + q) * 64) + w * 16 + m) * 8);
        acc = __builtin_amdgcn_mfma_f32_16x16x32_bf16(af, bf_, acc, 0, 0, 0);
    }
    #pragma unroll
    for (int rr = 0; rr < 4; rr++) {
        int li = q * 4 + rr;
        int nd = perm[blockIdx.x * 16 + li];
        int dO = deg_out[nd]; if (dO < 1) dO = 1;
        float s_ = rsqrtf((float)dO);
        __builtin_nontemporal_store(f2bf(acc[rr] * s_), &h2[(size_t)nd * 64 + w * 16 + m]);
    }
}

// ---- launch 5: layer-2 gather + projection, with the same sorted-index prefetch ----
__global__ __launch_bounds__(256) void gather2(const uint4* __restrict__ h2, const int* __restrict__ row_ptr,
                                               const u32* __restrict__ sorted, const float* __restrict__ b2,
                                               const float* __restrict__ Wf, const float* __restrict__ bfv,
                                               const int* __restrict__ perm,
                                               float* __restrict__ logits, float* __restrict__ hidden, int nNodes) {
    int g = (blockIdx.x * 256 + threadIdx.x) >> 3;
    int l = threadIdx.x & 7;
    if (g >= nNodes) return;
    int node = perm[g];
    int beg = row_ptr[node], end = row_ptr[node + 1];
    float a[8] = {0.f, 0.f, 0.f, 0.f, 0.f, 0.f, 0.f, 0.f};
    u32 s[8];
    #pragma unroll
    for (int j = 0; j < 8; j++) {
        int ee = beg + j; ee = (ee < end - 1) ? ee : end - 1;
        s[j] = sorted[ee];
    }
    for (int e = beg; e < end; e += 8) {
        int en = e + 8;
        u32 s2[8];
        if (en < end) {
            #pragma unroll
            for (int j = 0; j < 8; j++) {
                int ee = en + j; ee = (ee < end - 1) ? ee : end - 1;
                s2[j] = sorted[ee];
            }
        }
        uint4 p[8];
        #pragma unroll
        for (int j = 0; j < 8; j++)
            p[j] = h2[(size_t)(s[j] & 0xFFFFu) * 8 + l];
        #pragma unroll
        for (int j = 0; j < 8; j++)
            if (e + j < end) {
                a[0] += bflo(p[j].x); a[1] += bfhi(p[j].x);
                a[2] += bflo(p[j].y); a[3] += bfhi(p[j].y);
                a[4] += bflo(p[j].z); a[5] += bfhi(p[j].z);
                a[6] += bflo(p[j].w); a[7] += bfhi(p[j].w);
            }
        if (en < end) {
            #pragma unroll
            for (int j = 0; j < 8; j++) s[j] = s2[j];
        }
    }
    int dI = end - beg; if (dI < 1) dI = 1;
    float r = rsqrtf((float)dI);
    float v[8];
    #pragma unroll
    for (int f = 0; f < 8; f++) v[f] = a[f] * r + b2[8 * l + f];
    float4 oA = {v[0], v[1], v[2], v[3]};
    float4 oB = {v[4], v[5], v[6], v[7]};
    ((float4*)hidden)[(size_t)node * 16 + 2 * l + 0] = oA;
    ((float4*)hidden)[(size_t)node * 16 + 2 * l + 1] = oB;
    float l0 = 0.f, l1 = 0.f;
    #pragma unroll
    for (int f = 0; f < 8; f++) {
        l0 += v[f] * Wf[(8 * l + f) * 2 + 0];
        l1 += v[f] * Wf[(8 * l + f) * 2 + 1];
    }
    #pragma unroll
    for (int off = 4; off > 0; off >>= 1) {
        l0 += __shfl_down(l0, off, 8);
        l1 += __shfl_down(l1, off, 8);
    }
    if (l == 0) {
        logits[(size_t)node * 2 + 0] = l0 + bfv[0];
        logits[(size_t)node * 2 + 1] = l1 + bfv[1];
    }
}

extern "C" void kernel_launch(void* const* d_in, const int* in_sizes, int n_in,
                              void* d_out, int out_size, void* d_ws, size_t ws_size,
                              hipStream_t stream) {
    const float* x   = (const float*)d_in[0];
    const float* W1  = (const float*)d_in[1];
    const float* b1  = (const float*)d_in[2];
    const float* W2  = (const float*)d_in[3];
    const float* b2  = (const float*)d_in[4];
    const float* Wf  = (const float*)d_in[5];
    const float* bfv = (const float*)d_in[6];
    const int* src = (const int*)d_in[7];
    const int* dst = (const int*)d_in[8];

    float* out_logits = (float*)d_out;
    float* out_hidden = (float*)d_out + 2 * NNODES;

    char* ws = (char*)d_ws;
    size_t off = 0;
    auto alloc = [&](size_t bytes) { void* p = ws + off; off += (bytes + 255) & ~(size_t)255; return p; };
    u16*   gh1     = (u16*)alloc(NCH * NCH * 2);            // 128 KB, [chunk][digit]
    int*   part1   = (int*)alloc(256 * 4);
    u32*   sbuf    = (u32*)alloc((size_t)NEDGES * 4);
    u32*   sorted  = (u32*)alloc((size_t)NEDGES * 4);
    u32*   histS   = (u32*)alloc((size_t)SHB * 12500 * 4);  // 3.2 MB u8-packed partials
    u32*   histD   = (u32*)alloc((size_t)SHB * 12500 * 4);  // 3.2 MB
    int*   deg     = (int*)alloc(2 * NNODES * 4);           // [0..N)=deg_out, [N..2N)=deg_in
    int*   row_ptr = (int*)alloc((NNODES + 1) * 4);
    int*   gdh     = (int*)alloc(PBN * 64 * 4);
    int*   perm    = (int*)alloc(NNODES * 4);
    u16*   Wp1     = (u16*)alloc(256 * 128 * 2);
    u16*   Wp2     = (u16*)alloc(128 * 64 * 2);
    u16*   h       = (u16*)alloc((size_t)NNODES * 128 * 2);
    u16*   h2      = (u16*)alloc((size_t)NNODES * 64 * 2);

    int* deg_out = deg;
    int* deg_in  = deg + NNODES;

    // 1: u8 degree hists + partition hist (dst>>8) + weight prep (all uint4 edge loads)
    pre_kernel<<<2 * SHB + NCH + 128, 256, 0, stream>>>(W1, W2, Wp1, Wp2, src, dst, histS, histD, gh1, NEDGES);
    // 2: partition scatter + deg reduce + gdh (merged)
    scat_deg<<<NCH, 256, 0, stream>>>(src, dst, gh1, histS, histD, deg_out, deg_in, gdh, part1, sbuf, NEDGES);
    // 3: per-bucket counting sort + row_ptr || layer-1 gemm || perm scatter
    sort_gemm<<<NBUCK + GB1 + PBN, 256, 0, stream>>>(sbuf, part1, sorted, row_ptr, x, Wp1,
                                                     deg_out, deg_in, gdh, perm, h, NEDGES);
    // 4: layer-1 gather fused with layer-2 gemm (degree-balanced, prefetched)
    gather1f<<<NNODES / 16, 256, 0, stream>>>((const uint4*)h, row_ptr, sorted, b1, perm, deg_out, Wp2, h2);
    // 5: layer-2 gather + projection (degree-balanced, prefetched)
    gather2<<<(NNODES * 8 + 255) / 256, 256, 0, stream>>>((const uint4*)h2, row_ptr, sorted, b2, Wf, bfv,
                                                          perm, out_logits, out_hidden, NNODES);
}